// Round 7
// baseline (178.571 us; speedup 1.0000x reference)
//
#include <hip/hip_runtime.h>
#include <math.h>

#define NN 131072
#define KK 27
#define KP 28              // padded taps (tap 27 = zero weights)
#define FIN 3
#define FOUT 32
#define EPS 1e-5f

typedef _Float16 f16;
typedef __attribute__((ext_vector_type(8))) _Float16 f16x8;
typedef __attribute__((ext_vector_type(16))) float f32x16;

// ---------------------------------------------------------------------------
// Pack x_feats [N,3] f32 -> xp [N] float4 (w=0): one 16B gather per neighbor.
// ---------------------------------------------------------------------------
__global__ __launch_bounds__(256) void pack_x_kernel(
    const float* __restrict__ x, float4* __restrict__ xp)
{
    const int n = blockIdx.x * 256 + threadIdx.x;
    if (n < NN)
        xp[n] = make_float4(x[n * 3], x[n * 3 + 1], x[n * 3 + 2], 0.f);
}

// ---------------------------------------------------------------------------
// Pack w2 (f32 [27][32][32]) into f16 MFMA B-fragments, padded to 28 taps:
// w2p[k][half][lane][j]; B layout for v_mfma_f32_32x32x16:
//   col = lane&31, kdim = half*16 + (lane>>5)*8 + j.  Tap 27 = zeros.
// ---------------------------------------------------------------------------
__global__ __launch_bounds__(256) void pack_w2_kernel(
    const float* __restrict__ w2, f16* __restrict__ w2p)
{
    const int t = blockIdx.x * 256 + threadIdx.x;
    if (t >= KP * 1024) return;
    const int k    = t >> 10;          // 1024 elems per tap
    const int rem  = t & 1023;
    const int half = rem >> 9;
    const int l    = (rem >> 3) & 63;
    const int j    = rem & 7;
    const int krow = half * 16 + ((l >> 5) << 3) + j;  // input-feature row
    const int n    = l & 31;                           // output column
    w2p[t] = (k < KK) ? (f16)w2[k * (FOUT * FOUT) + krow * FOUT + n] : (f16)0.f;
}

// ---------------------------------------------------------------------------
// Phase 1: h = silu(bn1(einsum(x_feats[nbr_idx], w1))) -> [N,32] f16
// Block = 64 nodes: cooperative LDS staging of all 64*27 float4 rows (gathered
// once, ~1728 loads in flight), then wave w computes outputs [8w,8w+8).
// ---------------------------------------------------------------------------
__global__ __launch_bounds__(256) void conv1_kernel(
    const float4* __restrict__ xp,       // [N] packed x (w=0)
    const int*   __restrict__ nbr_idx,   // [N,27]
    const float* __restrict__ w1,        // [27,3,32]
    const float* __restrict__ g1,  const float* __restrict__ b1,
    const float* __restrict__ m1,  const float* __restrict__ v1,
    f16* __restrict__ h_out)             // [N,32] f16
{
    __shared__ float4 xs[64 * KK];                   // 27.6 KB

    const int tid  = threadIdx.x;
    const int nb0  = blockIdx.x * 64;                // first node of block

    // ---- stage: lds[i] = xp[nbr[base+i]], i = flat (node,tap) ----
    const int* nb = nbr_idx + (size_t)nb0 * KK;      // 1728 consecutive ints
    {
        int    idxv[7];
        float4 xv[7];
#pragma unroll
        for (int t = 0; t < 7; ++t) {                // coalesced idx loads
            const int i = t * 256 + tid;
            idxv[t] = (i < 64 * KK) ? nb[i] : 0;
        }
#pragma unroll
        for (int t = 0; t < 7; ++t)                  // 7 gathers in flight
            xv[t] = xp[idxv[t]];
#pragma unroll
        for (int t = 0; t < 7; ++t) {
            const int i = t * 256 + tid;
            if (i < 64 * KK) xs[i] = xv[t];
        }
    }
    __syncthreads();

    // ---- compute: wave w -> outputs [8w, 8w+8), lane l -> node nb0+l ----
    const int l  = tid & 63;
    const int ob = __builtin_amdgcn_readfirstlane((tid >> 6) * 8);

    float acc[8];
#pragma unroll
    for (int o = 0; o < 8; ++o) acc[o] = 0.f;

#pragma unroll 9
    for (int k = 0; k < KK; ++k) {
        const float4 xv = xs[l * KK + k];
        const float* w = w1 + k * (FIN * FOUT) + ob; // uniform -> s_load
#pragma unroll
        for (int o = 0; o < 8; ++o) {
            float a = acc[o];
            a = fmaf(xv.x, w[o],            a);
            a = fmaf(xv.y, w[FOUT + o],     a);
            a = fmaf(xv.z, w[2 * FOUT + o], a);
            acc[o] = a;
        }
    }

    f16x8 hv;
#pragma unroll
    for (int j = 0; j < 8; ++j) {
        const int o = ob + j;
        const float sc = g1[o] * rsqrtf(v1[o] + EPS);
        float v = (acc[j] - m1[o]) * sc + b1[o];
        v = v / (1.f + __expf(-v));                  // silu
        hv[j] = (f16)v;
    }
    *(f16x8*)(h_out + (size_t)(nb0 + l) * FOUT + ob) = hv;  // 16B store
}

// ---------------------------------------------------------------------------
// Phase 2 (MFMA, deep-pipelined): one wave = 32 nodes. B-fragments staged in
// LDS (so MFMA's B-reads use lgkmcnt, keeping the vmcnt queue = A-gathers
// only). A-gathers issued in 7-tap chunks, prefetched one chunk ahead ->
// ~14 outstanding line-misses per wave instead of ~3.
// ---------------------------------------------------------------------------
__global__ __launch_bounds__(256) void conv2_mfma_kernel(
    const f16*   __restrict__ h,         // [N,32] f16
    const int*   __restrict__ nbr_idx,   // [N,27]
    const f16*   __restrict__ w2p,       // packed [28][2][64][8] f16
    const float* __restrict__ z_feats,   // [N,3]
    const float* __restrict__ mlp_w,     // [3,32]
    const float* __restrict__ mlp_b,
    const float* __restrict__ mg, const float* __restrict__ mbe,
    const float* __restrict__ mm, const float* __restrict__ mv,
    float* __restrict__ out)             // [2,N,32]
{
    __shared__ f16 lb[KP * 1024];                    // 57344 B: all B-frags

    const int tid = threadIdx.x;

    // ---- stage all B fragments to LDS (coalesced, conflict-free) ----
    {
        const float4* src = (const float4*)w2p;      // 3584 float4
        float4* dst = (float4*)lb;
#pragma unroll
        for (int t = 0; t < 14; ++t)
            dst[t * 256 + tid] = src[t * 256 + tid];
    }
    __syncthreads();

    const int lane = tid & 63;
    const int wave = tid >> 6;
    const int base = (blockIdx.x * 4 + wave) * 32;   // this wave's node base
    const int row  = lane & 31;                      // A row
    const int hi   = lane >> 5;                      // k-half selector

    int idxs[KP];
    const int* nb = nbr_idx + (size_t)(base + row) * KK;
#pragma unroll
    for (int k = 0; k < KK; ++k) idxs[k] = nb[k];
    idxs[KK] = 0;                                    // pad tap (b = 0)

    f32x16 acc = {};
    const f16x8* lbp = (const f16x8*)lb;             // [k*128 + half*64 + lane]

    // prologue: chunk 0 gathers in flight
    f16x8 A1[7], A2[7];
#pragma unroll
    for (int t = 0; t < 7; ++t) {
        const f16* hr = h + (size_t)idxs[t] * FOUT + hi * 8;
        A1[t] = *(const f16x8*)hr;
        A2[t] = *(const f16x8*)(hr + 16);
    }

#pragma unroll
    for (int c = 0; c < 4; ++c) {
        f16x8 N1[7], N2[7];
        if (c < 3) {
#pragma unroll
            for (int t = 0; t < 7; ++t) {            // prefetch chunk c+1
                const f16* hr = h + (size_t)idxs[(c + 1) * 7 + t] * FOUT + hi * 8;
                N1[t] = *(const f16x8*)hr;
                N2[t] = *(const f16x8*)(hr + 16);
            }
        }
#pragma unroll
        for (int t = 0; t < 7; ++t) {                // consume chunk c
            const int k = c * 7 + t;
            const f16x8 b1 = lbp[k * 128 + lane];        // ds_read_b128
            const f16x8 b2 = lbp[k * 128 + 64 + lane];
            acc = __builtin_amdgcn_mfma_f32_32x32x16_f16(A1[t], b1, acc, 0, 0, 0);
            acc = __builtin_amdgcn_mfma_f32_32x32x16_f16(A2[t], b2, acc, 0, 0, 0);
        }
#pragma unroll
        for (int t = 0; t < 7; ++t) { A1[t] = N1[t]; A2[t] = N2[t]; }
    }

    // ---- epilogue: point branch for output column n0, fused add + store ----
    const int n0 = lane & 31;
    const float wc0 = mlp_w[n0];
    const float wc1 = mlp_w[FOUT + n0];
    const float wc2 = mlp_w[2 * FOUT + n0];
    const float sc  = mg[n0] * rsqrtf(mv[n0] + EPS);
    const float bi  = mlp_b[n0];
    const float mmv = mm[n0];
    const float mbv = mbe[n0];

#pragma unroll
    for (int r = 0; r < 16; ++r) {
        const int m    = (r & 3) + ((r >> 2) << 3) + (hi << 2); // C/D row map
        const int node = base + m;
        const float* zr = z_feats + (size_t)node * FIN;
        float z = bi;
        z = fmaf(zr[0], wc0, z);
        z = fmaf(zr[1], wc1, z);
        z = fmaf(zr[2], wc2, z);
        z = (z - mmv) * sc + mbv;
        z = fmaxf(z, 0.f);
        const float v = acc[r] + z;
        out[(size_t)node * FOUT + n0] = v;
        out[(size_t)NN * FOUT + (size_t)node * FOUT + n0] = v;
    }
}

extern "C" void kernel_launch(void* const* d_in, const int* in_sizes, int n_in,
                              void* d_out, int out_size, void* d_ws, size_t ws_size,
                              hipStream_t stream) {
    const float* x_feats = (const float*)d_in[0];
    const float* z_feats = (const float*)d_in[1];
    const int*   nbr_idx = (const int*)d_in[2];
    const float* w1      = (const float*)d_in[3];
    const float* bn1_g   = (const float*)d_in[4];
    const float* bn1_b   = (const float*)d_in[5];
    const float* bn1_m   = (const float*)d_in[6];
    const float* bn1_v   = (const float*)d_in[7];
    const float* w2      = (const float*)d_in[8];
    const float* mlp_w   = (const float*)d_in[9];
    const float* mlp_b   = (const float*)d_in[10];
    const float* mlp_g   = (const float*)d_in[11];
    const float* mlp_be  = (const float*)d_in[12];
    const float* mlp_m   = (const float*)d_in[13];
    const float* mlp_v   = (const float*)d_in[14];

    f16*    h   = (f16*)d_ws;                                     // 8 MiB
    f16*    w2p = (f16*)((char*)d_ws + (size_t)8 * 1024 * 1024);  // 56 KiB
    float4* xp  = (float4*)((char*)d_ws + (size_t)9 * 1024 * 1024); // 2 MiB
    float*  out = (float*)d_out;

    pack_x_kernel<<<NN / 256, 256, 0, stream>>>(x_feats, xp);
    pack_w2_kernel<<<(KP * 1024 + 255) / 256, 256, 0, stream>>>(w2, w2p);
    conv1_kernel<<<NN / 64, 256, 0, stream>>>(xp, nbr_idx, w1,
                                              bn1_g, bn1_b, bn1_m, bn1_v, h);
    conv2_mfma_kernel<<<NN / 128, 256, 0, stream>>>(h, nbr_idx, w2p, z_feats,
                                                    mlp_w, mlp_b, mlp_g, mlp_be,
                                                    mlp_m, mlp_v, out);
}

// Round 8
// 167.877 us; speedup vs baseline: 1.0637x; 1.0637x over previous
//
#include <hip/hip_runtime.h>
#include <math.h>

#define NN 131072
#define KK 27
#define FIN 3
#define FOUT 32
#define EPS 1e-5f

typedef _Float16 f16;
typedef __attribute__((ext_vector_type(8))) _Float16 f16x8;
typedef __attribute__((ext_vector_type(16))) float f32x16;

// ---------------------------------------------------------------------------
// Fused pack: (a) x_feats [N,3] f32 -> xp [N] float4 (one 16B gather per
// neighbor in conv1); (b) w2 f32 [27][32][32] -> f16 MFMA B-fragments
// w2p[k][half][lane][j], B layout: col = lane&31, kdim = half*16+(lane>>5)*8+j.
// ---------------------------------------------------------------------------
__global__ __launch_bounds__(256) void pack_kernel(
    const float* __restrict__ x, float4* __restrict__ xp,
    const float* __restrict__ w2, f16* __restrict__ w2p)
{
    const int t = blockIdx.x * 256 + threadIdx.x;
    if (t < NN)
        xp[t] = make_float4(x[t * 3], x[t * 3 + 1], x[t * 3 + 2], 0.f);
    if (t < KK * 1024) {
        const int k    = t >> 10;
        const int rem  = t & 1023;
        const int half = rem >> 9;
        const int l    = (rem >> 3) & 63;
        const int j    = rem & 7;
        const int krow = half * 16 + ((l >> 5) << 3) + j;
        const int n    = l & 31;
        w2p[t] = (f16)w2[k * (FOUT * FOUT) + krow * FOUT + n];
    }
}

// ---------------------------------------------------------------------------
// Phase 1: h = silu(bn1(einsum(x_feats[nbr_idx], w1))) -> [N,32] f16
// 1 thread/node (zero gather duplication), float4 gathers in 9-wide batches.
// Measured at the ~72G rows/s random-gather wall (~48.5 us).
// ---------------------------------------------------------------------------
__global__ __launch_bounds__(256) void conv1_kernel(
    const float4* __restrict__ xp,       // [N] packed x (w=0)
    const int*   __restrict__ nbr_idx,   // [N,27]
    const float* __restrict__ w1,        // [27,3,32]
    const float* __restrict__ g1,  const float* __restrict__ b1,
    const float* __restrict__ m1,  const float* __restrict__ v1,
    f16* __restrict__ h_out)             // [N,32] f16
{
    const int n = blockIdx.x * 256 + threadIdx.x;

    int idxs[KK];
    const int* nb = nbr_idx + (size_t)n * KK;
#pragma unroll
    for (int k = 0; k < KK; ++k) idxs[k] = nb[k];   // break idx->gather chain

    float acc[FOUT];
#pragma unroll
    for (int o = 0; o < FOUT; ++o) acc[o] = 0.f;

#pragma unroll
    for (int c = 0; c < 3; ++c) {                   // 3 chunks of 9 taps
        float4 xs[9];
#pragma unroll
        for (int q = 0; q < 9; ++q)                 // 9 dwordx4 in flight
            xs[q] = xp[idxs[c * 9 + q]];
#pragma unroll
        for (int q = 0; q < 9; ++q) {
            const float* w = w1 + (c * 9 + q) * (FIN * FOUT); // uniform->s_load
#pragma unroll
            for (int o = 0; o < FOUT; ++o) {
                float a = acc[o];
                a = fmaf(xs[q].x, w[o],            a);
                a = fmaf(xs[q].y, w[FOUT + o],     a);
                a = fmaf(xs[q].z, w[2 * FOUT + o], a);
                acc[o] = a;
            }
        }
    }

    f16* hr = h_out + (size_t)n * FOUT;
#pragma unroll
    for (int g = 0; g < 4; ++g) {
        f16x8 hv;
#pragma unroll
        for (int j = 0; j < 8; ++j) {
            const int o = g * 8 + j;
            const float sc = g1[o] * rsqrtf(v1[o] + EPS);
            float v = (acc[o] - m1[o]) * sc + b1[o];
            v = v / (1.f + __expf(-v));              // silu
            hv[j] = (f16)v;
        }
        *(f16x8*)(hr + g * 8) = hv;                  // 16B stores
    }
}

// ---------------------------------------------------------------------------
// Phase 2 (MFMA): x_out = einsum(h[nbr_idx], w2) via v_mfma_f32_32x32x16_f16.
// One wave = 32 nodes; per tap a gathered 32x32 f16 A-tile (each lane one
// disjoint 16B chunk) x packed B-frag, 2 MFMA. Point-branch fused in epilogue.
// Measured at the ~72G rows/s random-gather wall (~49.3 us); deeper pipelines,
// split-K, and LDS-B all measured neutral-or-worse (R4/R6/R7).
// ---------------------------------------------------------------------------
__global__ __launch_bounds__(256) void conv2_mfma_kernel(
    const f16*   __restrict__ h,         // [N,32] f16
    const int*   __restrict__ nbr_idx,   // [N,27]
    const f16*   __restrict__ w2p,       // packed [27][2][64][8] f16
    const float* __restrict__ z_feats,   // [N,3]
    const float* __restrict__ mlp_w,     // [3,32]
    const float* __restrict__ mlp_b,
    const float* __restrict__ mg, const float* __restrict__ mbe,
    const float* __restrict__ mm, const float* __restrict__ mv,
    float* __restrict__ out)             // [2,N,32]
{
    const int lane = threadIdx.x & 63;
    const int wave = threadIdx.x >> 6;
    const int base = (blockIdx.x * 4 + wave) * 32;   // this wave's node base
    const int row  = lane & 31;                      // A row
    const int hi   = lane >> 5;                      // which k-half of 8

    int idxs[KK];
    const int* nb = nbr_idx + (size_t)(base + row) * KK;
#pragma unroll
    for (int k = 0; k < KK; ++k) idxs[k] = nb[k];

    f32x16 acc = {};

    const f16x8* bp = (const f16x8*)w2p;             // [k*128 + half*64 + lane]
#pragma unroll 3
    for (int k = 0; k < KK; ++k) {
        const f16* hr = h + (size_t)idxs[k] * FOUT + hi * 8;
        const f16x8 a1 = *(const f16x8*)hr;          // feats [0..16) half
        const f16x8 a2 = *(const f16x8*)(hr + 16);   // feats [16..32) half
        const f16x8 b1 = bp[k * 128 + lane];
        const f16x8 b2 = bp[k * 128 + 64 + lane];
        acc = __builtin_amdgcn_mfma_f32_32x32x16_f16(a1, b1, acc, 0, 0, 0);
        acc = __builtin_amdgcn_mfma_f32_32x32x16_f16(a2, b2, acc, 0, 0, 0);
    }

    // ---- epilogue: point branch for output column n0, fused add + store ----
    const int n0 = lane & 31;
    const float wc0 = mlp_w[n0];
    const float wc1 = mlp_w[FOUT + n0];
    const float wc2 = mlp_w[2 * FOUT + n0];
    const float sc  = mg[n0] * rsqrtf(mv[n0] + EPS);
    const float bi  = mlp_b[n0];
    const float mmv = mm[n0];
    const float mbv = mbe[n0];

#pragma unroll
    for (int r = 0; r < 16; ++r) {
        const int m    = (r & 3) + ((r >> 2) << 3) + (hi << 2); // C/D row map
        const int node = base + m;
        const float* zr = z_feats + (size_t)node * FIN;
        float z = bi;
        z = fmaf(zr[0], wc0, z);
        z = fmaf(zr[1], wc1, z);
        z = fmaf(zr[2], wc2, z);
        z = (z - mmv) * sc + mbv;
        z = fmaxf(z, 0.f);
        const float v = acc[r] + z;
        out[(size_t)node * FOUT + n0] = v;
        out[(size_t)NN * FOUT + (size_t)node * FOUT + n0] = v;
    }
}

extern "C" void kernel_launch(void* const* d_in, const int* in_sizes, int n_in,
                              void* d_out, int out_size, void* d_ws, size_t ws_size,
                              hipStream_t stream) {
    const float* x_feats = (const float*)d_in[0];
    const float* z_feats = (const float*)d_in[1];
    const int*   nbr_idx = (const int*)d_in[2];
    const float* w1      = (const float*)d_in[3];
    const float* bn1_g   = (const float*)d_in[4];
    const float* bn1_b   = (const float*)d_in[5];
    const float* bn1_m   = (const float*)d_in[6];
    const float* bn1_v   = (const float*)d_in[7];
    const float* w2      = (const float*)d_in[8];
    const float* mlp_w   = (const float*)d_in[9];
    const float* mlp_b   = (const float*)d_in[10];
    const float* mlp_g   = (const float*)d_in[11];
    const float* mlp_be  = (const float*)d_in[12];
    const float* mlp_m   = (const float*)d_in[13];
    const float* mlp_v   = (const float*)d_in[14];

    f16*    h   = (f16*)d_ws;                                     // 8 MiB
    f16*    w2p = (f16*)((char*)d_ws + (size_t)8 * 1024 * 1024);  // 54 KiB
    float4* xp  = (float4*)((char*)d_ws + (size_t)9 * 1024 * 1024); // 2 MiB
    float*  out = (float*)d_out;

    pack_kernel<<<NN / 256, 256, 0, stream>>>(x_feats, xp, w2, w2p);
    conv1_kernel<<<NN / 256, 256, 0, stream>>>(xp, nbr_idx, w1,
                                               bn1_g, bn1_b, bn1_m, bn1_v, h);
    conv2_mfma_kernel<<<NN / 128, 256, 0, stream>>>(h, nbr_idx, w2p, z_feats,
                                                    mlp_w, mlp_b, mlp_g, mlp_be,
                                                    mlp_m, mlp_v, out);
}